// Round 9
// baseline (254.344 us; speedup 1.0000x reference)
//
#include <hip/hip_runtime.h>
#include <hip/hip_bf16.h>

// 2-layer GCN: out = A_hat @ relu((A_hat@X)@W1 + b1) @ W2 + b2,  A_hat = D^-1/2 (A+I) D^-1/2
// R9: gemm12 software-pipelined -- R8's VGPR_Count=52 showed the compiler issued each
//     tile's B loads right before their MFMAs (serial load->mfma chains, MfmaUtil 5%).
//     Now: __launch_bounds__(256,3) raises the reg budget to ~170; B(t+1) is explicitly
//     preloaded during tile t's MFMAs; phase-B's first W2 tile is fetched BEFORE the
//     barrier so the sync drain overlaps global loads.
// bf16 activations/gathers, fp32 accumulation everywhere.

static constexpr int N_NODES = 50000;
static constexpr int N_EDGES = 800000;
static constexpr int F_IN = 128;
static constexpr int HID  = 256;
static constexpr int F_OUT = 128;
static constexpr int H2P  = HID + 8;   // LDS pitch (shorts) for h2 tile

typedef __attribute__((ext_vector_type(8))) short short8;   // 8 bf16 raw bits (4 VGPRs)
typedef __attribute__((ext_vector_type(4))) float f32x4;

__device__ __forceinline__ unsigned short f2bf(float f) {   // RNE fp32->bf16
    union { float f; unsigned u; } x; x.f = f;
    unsigned r = x.u + 0x7FFF + ((x.u >> 16) & 1);
    return (unsigned short)(r >> 16);
}
__device__ __forceinline__ float bf2f(unsigned short h) {
    union { unsigned u; float f; } x; x.u = ((unsigned)h) << 16;
    return x.f;
}

// Fused independent prep: deg/pos atomics  |  W1^T  |  W2^T   (grid-partitioned)
__global__ void deg_wt_kernel(const int* __restrict__ dst, int* __restrict__ deg,
                              int* __restrict__ pos, int E,
                              const float* __restrict__ W1, unsigned short* __restrict__ w1t,
                              const float* __restrict__ W2, unsigned short* __restrict__ w2t,
                              int EB, int NB1) {
    const int b = blockIdx.x;
    if (b < EB) {
        int i = b * 256 + threadIdx.x;
        if (i < E) pos[i] = atomicAdd(&deg[dst[i]], 1);
    } else if (b < EB + NB1) {
        int t = (b - EB) * 256 + threadIdx.x;       // W1: F_IN rows x HID cols -> w1t[HID][F_IN]
        if (t < F_IN * HID) {
            int n = t / F_IN, k = t - n * F_IN;
            w1t[t] = f2bf(W1[(size_t)k * HID + n]);
        }
    } else {
        int t = (b - EB - NB1) * 256 + threadIdx.x; // W2: HID rows x F_OUT cols -> w2t[F_OUT][HID]
        if (t < HID * F_OUT) {
            int n = t / HID, k = t - n * HID;
            w2t[t] = f2bf(W2[(size_t)k * F_OUT + n]);
        }
    }
}

// Fused: per-block sum of deg -> bsums, plus dinv[i] = rsqrt(deg+1).
__global__ __launch_bounds__(256) void scan_reduce_dinv(const int* __restrict__ deg,
                                                        int* __restrict__ bsums,
                                                        float* __restrict__ dinv, int N) {
    int i = blockIdx.x * 256 + threadIdx.x;
    int v = (i < N) ? deg[i] : 0;
    if (i < N) dinv[i] = rsqrtf((float)(v + 1));   // +1 = self loop
#pragma unroll
    for (int ofs = 32; ofs > 0; ofs >>= 1) v += __shfl_down(v, ofs);
    __shared__ int ws[4];
    if ((threadIdx.x & 63) == 0) ws[threadIdx.x >> 6] = v;
    __syncthreads();
    if (threadIdx.x == 0) bsums[blockIdx.x] = ws[0] + ws[1] + ws[2] + ws[3];
}

// Fused: blocks [0,nb): redundant LDS scan of bsums + intra-block scan of deg -> off;
// blocks [nb, ...): xs = bf16(dinv * x)  (dinv ready since scan_reduce_dinv).
__global__ __launch_bounds__(256) void scan_final_scalex(const int* __restrict__ deg,
                                                         const int* __restrict__ bsums,
                                                         int* __restrict__ off, int N, int nb,
                                                         const float* __restrict__ x,
                                                         const float* __restrict__ dinv,
                                                         unsigned short* __restrict__ xs) {
    const int tid = threadIdx.x;
    if ((int)blockIdx.x >= nb) {   // scalex partition
        int i = (blockIdx.x - nb) * 256 + tid;     // one thread per 8 elems
        if (i < N_NODES * F_IN / 8) {
            float dv = dinv[i >> 4];
            float4 v0 = ((const float4*)x)[i * 2];
            float4 v1 = ((const float4*)x)[i * 2 + 1];
            short8 o;
            o[0] = (short)f2bf(v0.x * dv); o[1] = (short)f2bf(v0.y * dv);
            o[2] = (short)f2bf(v0.z * dv); o[3] = (short)f2bf(v0.w * dv);
            o[4] = (short)f2bf(v1.x * dv); o[5] = (short)f2bf(v1.y * dv);
            o[6] = (short)f2bf(v1.z * dv); o[7] = (short)f2bf(v1.w * dv);
            *(short8*)(xs + (size_t)i * 8) = o;
        }
        return;
    }
    __shared__ int bs[256];
    __shared__ int s[256];
    bs[tid] = (tid < nb) ? bsums[tid] : 0;
    const int i = blockIdx.x * 256 + tid;
    int v = (i < N) ? deg[i] : 0;
    s[tid] = v;
    __syncthreads();
    for (int ofs = 1; ofs < 256; ofs <<= 1) {
        int tb = (tid >= ofs) ? bs[tid - ofs] : 0;
        int tv = (tid >= ofs) ? s[tid - ofs] : 0;
        __syncthreads();
        bs[tid] += tb;
        s[tid] += tv;
        __syncthreads();
    }
    int bbase = (blockIdx.x == 0) ? 0 : bs[blockIdx.x - 1];
    int excl = (tid == 0) ? 0 : s[tid - 1];
    if (i <= N) off[i] = bbase + excl;
}

// Pure scatter: csr[off[dst] + pos] = src.  No atomics.
__global__ void scatter_kernel(const int* __restrict__ src, const int* __restrict__ dst,
                               const int* __restrict__ pos, const int* __restrict__ off,
                               int* __restrict__ csr, int E) {
    int i = blockIdx.x * blockDim.x + threadIdx.x;
    if (i < E) csr[off[dst[i]] + pos[i]] = src[i];
}

// Wave-per-node aggregation over 128-dim bf16 rows, fp32 accumulate.
// Wave = 4 edge-slots x 16 lanes (ushort8 / 16 B per lane); 4 nodes per 256-block.
// Predicated-batch loop: each batch issues 4 clamped loads per slot (16 per wave).
// MODE 0: out_bf16[n] = bf16( dinv[n] * (self + sum) )
// MODE 1: out_f32[n]  = dinv[n] * (self + sum) + bias
template <int MODE>
__global__ __launch_bounds__(256) void agg_bf16(const unsigned short* __restrict__ hs,
                                                const int* __restrict__ off,
                                                const int* __restrict__ csr,
                                                const float* __restrict__ dinv,
                                                const float* __restrict__ bias,
                                                void* __restrict__ outp, int N) {
    const int wid = threadIdx.x >> 6;
    const int n = blockIdx.x * 4 + wid;
    if (n >= N) return;
    const int lane = threadIdx.x & 63;
    const int lane16 = lane & 15;
    const int slot = lane >> 4;   // 0..3

    float va[8], vb[8], vc[8], vd[8];
#pragma unroll
    for (int j = 0; j < 8; j++) { va[j] = 0.f; vb[j] = 0.f; vc[j] = 0.f; vd[j] = 0.f; }

    if (slot == 0) {  // self loop
        short8 s = *(const short8*)(hs + (size_t)n * 128 + lane16 * 8);
#pragma unroll
        for (int j = 0; j < 8; j++) va[j] = bf2f((unsigned short)s[j]);
    }

    const int e0 = off[n];
    const int e1 = off[n + 1];
    for (int e = e0 + slot; e < e1; e += 16) {
        const int i1 = e + 4, i2 = e + 8, i3 = e + 12;
        const float f1 = (i1 < e1) ? 1.f : 0.f;
        const float f2 = (i2 < e1) ? 1.f : 0.f;
        const float f3 = (i3 < e1) ? 1.f : 0.f;
        const int c1 = min(i1, e1 - 1), c2 = min(i2, e1 - 1), c3 = min(i3, e1 - 1);
        int s0 = csr[e];
        int s1 = csr[c1];
        int s2 = csr[c2];
        int s3 = csr[c3];
        short8 v0 = *(const short8*)(hs + (size_t)s0 * 128 + lane16 * 8);
        short8 v1 = *(const short8*)(hs + (size_t)s1 * 128 + lane16 * 8);
        short8 v2 = *(const short8*)(hs + (size_t)s2 * 128 + lane16 * 8);
        short8 v3 = *(const short8*)(hs + (size_t)s3 * 128 + lane16 * 8);
#pragma unroll
        for (int j = 0; j < 8; j++) va[j] += bf2f((unsigned short)v0[j]);
#pragma unroll
        for (int j = 0; j < 8; j++) vb[j] = fmaf(f1, bf2f((unsigned short)v1[j]), vb[j]);
#pragma unroll
        for (int j = 0; j < 8; j++) vc[j] = fmaf(f2, bf2f((unsigned short)v2[j]), vc[j]);
#pragma unroll
        for (int j = 0; j < 8; j++) vd[j] = fmaf(f3, bf2f((unsigned short)v3[j]), vd[j]);
    }
#pragma unroll
    for (int j = 0; j < 8; j++) va[j] += vb[j] + vc[j] + vd[j];

#pragma unroll
    for (int j = 0; j < 8; j++) va[j] += __shfl_down(va[j], 32);
#pragma unroll
    for (int j = 0; j < 8; j++) va[j] += __shfl_down(va[j], 16);

    if (lane < 16) {
        float dv = dinv[n];
        if (MODE == 0) {
            short8 o;
#pragma unroll
            for (int j = 0; j < 8; j++) o[j] = (short)f2bf(va[j] * dv);
            *(short8*)((unsigned short*)outp + (size_t)n * 128 + lane * 8) = o;
        } else {
            float* op = (float*)outp + (size_t)n * 128 + lane * 8;
            float4 o0, o1;
            o0.x = va[0] * dv + bias[lane * 8 + 0];
            o0.y = va[1] * dv + bias[lane * 8 + 1];
            o0.z = va[2] * dv + bias[lane * 8 + 2];
            o0.w = va[3] * dv + bias[lane * 8 + 3];
            o1.x = va[4] * dv + bias[lane * 8 + 4];
            o1.y = va[5] * dv + bias[lane * 8 + 5];
            o1.z = va[6] * dv + bias[lane * 8 + 6];
            o1.w = va[7] * dv + bias[lane * 8 + 7];
            ((float4*)op)[0] = o0;
            ((float4*)op)[1] = o1;
        }
    }
}

// Fused double GEMM, software-pipelined: hs2 = dinv * ( relu(Y@W1 + b1) @ W2 ).
// 64-row block, 4 waves = 2 rowgrp x 2 colgrp.  Phase A: 8 col tiles, B(t+1) preloaded
// during tile t's MFMAs.  Phase-B tile-0 W2 frags fetched BEFORE the barrier.
// Phase B: A frags from LDS (ds_read_b128), 4 col tiles, same pipelining.
// Frag layouts: A/B m(n)=lane&15, k=q*8+j;  D col=lane&15, row=q*4+reg.
__global__ __launch_bounds__(256, 3) void gemm12(const unsigned short* __restrict__ Y,
                                                 const unsigned short* __restrict__ w1t,
                                                 const float* __restrict__ b1,
                                                 const unsigned short* __restrict__ w2t,
                                                 const float* __restrict__ dinv,
                                                 unsigned short* __restrict__ hs2, int M) {
    __shared__ unsigned short h2s[64 * H2P];   // 33792 B

    const int wid = threadIdx.x >> 6;
    const int lane = threadIdx.x & 63;
    const int an = lane & 15;
    const int q = lane >> 4;
    const int rowgrp = wid & 1;
    const int colgrp = wid >> 1;
    const int m0 = blockIdx.x * 64 + rowgrp * 32;
    const int lrow0 = rowgrp * 32;

    // ---- Phase A: h2 = relu(Y@W1+b1) -> LDS, pipelined over 8 tiles ----
    {
        short8 a[2][4];
#pragma unroll
        for (int r = 0; r < 2; r++) {
            int row = m0 + r * 16 + an;
            if (row >= M) row = M - 1;
            const unsigned short* xp = Y + (size_t)row * F_IN + q * 8;
#pragma unroll
            for (int c = 0; c < 4; c++) a[r][c] = *(const short8*)(xp + c * 32);
        }
        const int colbase = colgrp * 8;
        short8 bcur[4], bnxt[4];
        {
            const unsigned short* wp = w1t + (size_t)((colbase + 0) * 16 + an) * F_IN + q * 8;
#pragma unroll
            for (int c = 0; c < 4; c++) bcur[c] = *(const short8*)(wp + c * 32);
        }
#pragma unroll
        for (int t = 0; t < 8; t++) {
            if (t < 7) {
                const unsigned short* wp = w1t + (size_t)((colbase + t + 1) * 16 + an) * F_IN + q * 8;
#pragma unroll
                for (int c = 0; c < 4; c++) bnxt[c] = *(const short8*)(wp + c * 32);
            }
            f32x4 acc0 = {0.f, 0.f, 0.f, 0.f};
            f32x4 acc1 = {0.f, 0.f, 0.f, 0.f};
#pragma unroll
            for (int c = 0; c < 4; c++) {
                acc0 = __builtin_amdgcn_mfma_f32_16x16x32_bf16(a[0][c], bcur[c], acc0, 0, 0, 0);
                acc1 = __builtin_amdgcn_mfma_f32_16x16x32_bf16(a[1][c], bcur[c], acc1, 0, 0, 0);
            }
            const int col = (colbase + t) * 16 + an;
            const float bv = b1[col];
#pragma unroll
            for (int rr = 0; rr < 4; rr++) {
                h2s[(lrow0 + q * 4 + rr) * H2P + col]      = f2bf(fmaxf(acc0[rr] + bv, 0.f));
                h2s[(lrow0 + 16 + q * 4 + rr) * H2P + col] = f2bf(fmaxf(acc1[rr] + bv, 0.f));
            }
#pragma unroll
            for (int c = 0; c < 4; c++) bcur[c] = bnxt[c];
        }
    }

    // Prefetch phase-B tile 0 W2 frags BEFORE the barrier (independent of LDS).
    short8 ccur[8], cnxt[8];
    {
        const unsigned short* wp = w2t + (size_t)((colgrp * 4 + 0) * 16 + an) * HID + q * 8;
#pragma unroll
        for (int c = 0; c < 8; c++) ccur[c] = *(const short8*)(wp + c * 32);
    }
    __syncthreads();

    // ---- Phase B: hs2 = dinv * (h2 @ W2), pipelined over 4 tiles ----
    {
        short8 a[2][8];
#pragma unroll
        for (int r = 0; r < 2; r++) {
            const unsigned short* hp = &h2s[(lrow0 + r * 16 + an) * H2P + q * 8];
#pragma unroll
            for (int c = 0; c < 8; c++) a[r][c] = *(const short8*)(hp + c * 32);
        }
#pragma unroll
        for (int t = 0; t < 4; t++) {
            if (t < 3) {
                const unsigned short* wp = w2t + (size_t)((colgrp * 4 + t + 1) * 16 + an) * HID + q * 8;
#pragma unroll
                for (int c = 0; c < 8; c++) cnxt[c] = *(const short8*)(wp + c * 32);
            }
            f32x4 acc0 = {0.f, 0.f, 0.f, 0.f};
            f32x4 acc1 = {0.f, 0.f, 0.f, 0.f};
#pragma unroll
            for (int c = 0; c < 8; c++) {
                acc0 = __builtin_amdgcn_mfma_f32_16x16x32_bf16(a[0][c], ccur[c], acc0, 0, 0, 0);
                acc1 = __builtin_amdgcn_mfma_f32_16x16x32_bf16(a[1][c], ccur[c], acc1, 0, 0, 0);
            }
            const int col = (colgrp * 4 + t) * 16 + an;
#pragma unroll
            for (int rr = 0; rr < 4; rr++) {
                int m = m0 + q * 4 + rr;
                if (m < M) hs2[(size_t)m * F_OUT + col] = f2bf(acc0[rr] * dinv[m]);
                int m2 = m0 + 16 + q * 4 + rr;
                if (m2 < M) hs2[(size_t)m2 * F_OUT + col] = f2bf(acc1[rr] * dinv[m2]);
            }
#pragma unroll
            for (int c = 0; c < 8; c++) ccur[c] = cnxt[c];
        }
    }
}

extern "C" void kernel_launch(void* const* d_in, const int* in_sizes, int n_in,
                              void* d_out, int out_size, void* d_ws, size_t ws_size,
                              hipStream_t stream) {
    const float* x  = (const float*)d_in[0];
    const int*   ei = (const int*)d_in[1];   // [2,E] int32
    const float* W1 = (const float*)d_in[2];
    const float* b1 = (const float*)d_in[3];
    const float* W2 = (const float*)d_in[4];
    const float* b2 = (const float*)d_in[5];

    const int N = N_NODES;
    const int E = N_EDGES;
    const int* srcp = ei;
    const int* dstp = ei + E;

    char* base = (char*)d_ws;
    size_t o = 0;
    auto alloc = [&](size_t bytes) {
        void* p = base + o;
        o = (o + bytes + 255) & ~(size_t)255;
        return p;
    };
    int*            deg  = (int*)alloc((size_t)N * 4);
    int*            offs = (int*)alloc((size_t)(N + 1) * 4);
    float*          dinv = (float*)alloc((size_t)N * 4);
    int*            bsum = (int*)alloc(256 * 4);
    int*            pos  = (int*)alloc((size_t)E * 4);
    int*            csr  = (int*)alloc((size_t)E * 4);
    unsigned short* xs   = (unsigned short*)alloc((size_t)N * F_IN * 2);  // dinv*x, bf16
    unsigned short* Y    = (unsigned short*)alloc((size_t)N * F_IN * 2);  // A_hat@X, bf16
    unsigned short* w1t  = (unsigned short*)alloc((size_t)F_IN * HID * 2);
    unsigned short* w2t  = (unsigned short*)alloc((size_t)HID * F_OUT * 2);
    unsigned short* hs2  = xs;  // xs dead after agg1

    hipMemsetAsync(deg, 0, (size_t)N * 4, stream);

    const int NB  = (N + 256) / 256;           // 196, covers i==N in scan_final
    const int NBX = (N * F_IN / 8 + 255) / 256;
    const int EB  = (E + 255) / 256;
    const int NB1 = (F_IN * HID + 255) / 256;
    const int NB2 = (HID * F_OUT + 255) / 256;

    deg_wt_kernel<<<EB + NB1 + NB2, 256, 0, stream>>>(dstp, deg, pos, E, W1, w1t, W2, w2t, EB, NB1);
    scan_reduce_dinv<<<NB, 256, 0, stream>>>(deg, bsum, dinv, N);
    scan_final_scalex<<<NB + NBX, 256, 0, stream>>>(deg, bsum, offs, N, NB, x, dinv, xs);
    scatter_kernel<<<EB, 256, 0, stream>>>(srcp, dstp, pos, offs, csr, E);

    // layer 1 agg: Y = A_hat@X (bf16 gather)
    agg_bf16<0><<<(N + 3) / 4, 256, 0, stream>>>(xs, offs, csr, dinv, nullptr, Y, N);
    // fused GEMMs: hs2 = dinv * ( relu(Y@W1+b1) @ W2 )
    gemm12<<<(N + 63) / 64, 256, 0, stream>>>(Y, w1t, b1, w2t, dinv, hs2, N);
    // layer 2 agg: out = dinv*(hs2[self]+gather) + b2
    agg_bf16<1><<<(N + 3) / 4, 256, 0, stream>>>(hs2, offs, csr, dinv, b2, d_out, N);
}